// Round 14
// baseline (77.343 us; speedup 1.0000x reference)
//
#include <hip/hip_runtime.h>
#include <hip/hip_fp16.h>

#define B_ 2
#define N_ 6
#define D_ 41
#define H_ 16
#define W_ 44
#define C_ 64
#define X_ 200
#define Y_ 200
#define NPTS (B_*N_*D_*H_*W_)   // 346368 (multiple of 8)
#define NBN (B_*N_)             // 12
#define NCELL (B_*X_*Y_)        // 80000
#define MAT_STRIDE 24
#define KREP 4                  // stage replicas (hot-line contention / KREP)

// Deterministic HW packed-fp16 atomic add (gfx90a+/gfx950): 2 channels per op.
__device__ inline void pk_add_f16(__half2* addr, __half2 val) {
    unsigned int u = *reinterpret_cast<unsigned int*>(&val);
    asm volatile("global_atomic_pk_add_f16 %0, %1, off"
                 :: "v"((unsigned long long)(uintptr_t)addr), "v"(u)
                 : "memory");
}

__device__ inline void inv3x3(const double m[9], double out[9]) {
    double a=m[0],b=m[1],c=m[2],d=m[3],e=m[4],f=m[5],g=m[6],h=m[7],i=m[8];
    double A  =  (e*i - f*h);
    double Bm = -(d*i - f*g);
    double Cm =  (d*h - e*g);
    double det = a*A + b*Bm + c*Cm;
    double id = 1.0/det;
    out[0] = A*id;   out[1] = -(b*i - c*h)*id; out[2] =  (b*f - c*e)*id;
    out[3] = Bm*id;  out[4] =  (a*i - c*g)*id; out[5] = -(a*f - c*d)*id;
    out[6] = Cm*id;  out[7] = -(a*h - b*g)*id; out[8] =  (a*e - b*d)*id;
}

// One thread per (b,n): inv(post_rots), comb = rot(inv(extr)) @ inv(K), trans.
__global__ void prep_kernel(const float* __restrict__ post_rots,
                            const float* __restrict__ intr,
                            const float* __restrict__ extr,
                            double* __restrict__ mats) {
    int bn = threadIdx.x;
    if (bn >= NBN) return;

    double pr[9], prinv[9], kk[9], kin[9];
    for (int i=0;i<9;i++) pr[i] = (double)post_rots[bn*9+i];
    inv3x3(pr, prinv);
    for (int i=0;i<9;i++) kk[i] = (double)intr[bn*9+i];
    inv3x3(kk, kin);

    const float* E = extr + bn*16;
    double a00=E[0], a01=E[1], a02=E[2], a03=E[3];
    double a10=E[4], a11=E[5], a12=E[6], a13=E[7];
    double a20=E[8], a21=E[9], a22=E[10], a23=E[11];
    double a30=E[12], a31=E[13], a32=E[14], a33=E[15];

    double s0=a00*a11-a10*a01, s1=a00*a12-a10*a02, s2=a00*a13-a10*a03;
    double s3=a01*a12-a11*a02, s4=a01*a13-a11*a03, s5=a02*a13-a12*a03;
    double c5=a22*a33-a32*a23, c4=a21*a33-a31*a23, c3=a21*a32-a31*a22;
    double c2=a20*a33-a30*a23, c1=a20*a32-a30*a22, c0=a20*a31-a30*a21;
    double det = s0*c5 - s1*c4 + s2*c3 + s3*c2 - s4*c1 + s5*c0;
    double iv = 1.0/det;

    double rot[9], trans[3];
    rot[0] = ( a11*c5 - a12*c4 + a13*c3)*iv;
    rot[1] = (-a01*c5 + a02*c4 - a03*c3)*iv;
    rot[2] = ( a31*s5 - a32*s4 + a33*s3)*iv;
    trans[0]=(-a21*s5 + a22*s4 - a23*s3)*iv;
    rot[3] = (-a10*c5 + a12*c2 - a13*c1)*iv;
    rot[4] = ( a00*c5 - a02*c2 + a03*c1)*iv;
    rot[5] = (-a30*s5 + a32*s2 - a33*s1)*iv;
    trans[1]=( a20*s5 - a22*s2 + a23*s1)*iv;
    rot[6] = ( a10*c4 - a11*c2 + a13*c0)*iv;
    rot[7] = (-a00*c4 + a01*c2 - a03*c0)*iv;
    rot[8] = ( a30*s4 - a31*s2 + a33*s0)*iv;
    trans[2]=(-a20*s4 + a21*s2 - a23*s0)*iv;

    double comb[9];
    for (int i=0;i<3;i++) for (int j=0;j<3;j++)
        comb[i*3+j] = rot[i*3+0]*kin[0+j] + rot[i*3+1]*kin[3+j] + rot[i*3+2]*kin[6+j];

    double* o = mats + (size_t)bn*MAT_STRIDE;
    for (int i=0;i<9;i++) o[i]   = prinv[i];
    for (int i=0;i<9;i++) o[9+i] = comb[i];
    for (int i=0;i<3;i++) o[18+i]= trans[i];
}

// One THREAD per point: cell id (or -1).
__global__ __launch_bounds__(256)
void geom_kernel(const float* __restrict__ post_trans,
                 const float* __restrict__ frustum,
                 const float* __restrict__ bev_res,
                 const float* __restrict__ bev_start,
                 const double* __restrict__ mats,
                 int* __restrict__ rank) {
    int p = blockIdx.x * blockDim.x + threadIdx.x;
    if (p >= NPTS) return;

    int w = p % W_; int t = p / W_;
    int h = t % H_;  t /= H_;
    int d = t % D_;  t /= D_;
    int bn = t;      int b = bn / N_;

    const double* M = mats + (size_t)bn*MAT_STRIDE;
    int fidx = ((d*H_ + h)*W_ + w)*3;
    double fx = (double)frustum[fidx+0];
    double fy = (double)frustum[fidx+1];
    double fz = (double)frustum[fidx+2];

    double px = fx - (double)post_trans[bn*3+0];
    double py = fy - (double)post_trans[bn*3+1];
    double pz = fz - (double)post_trans[bn*3+2];

    double q0 = M[0]*px + M[1]*py + M[2]*pz;
    double q1 = M[3]*px + M[4]*py + M[5]*pz;
    double q2 = M[6]*px + M[7]*py + M[8]*pz;

    double r0 = q0*q2, r1 = q1*q2, r2 = q2;

    double gx = M[9]*r0  + M[10]*r1 + M[11]*r2 + M[18];
    double gy = M[12]*r0 + M[13]*r1 + M[14]*r2 + M[19];
    double gz = M[15]*r0 + M[16]*r1 + M[17]*r2 + M[20];

    double resx = (double)bev_res[0], resy = (double)bev_res[1], resz = (double)bev_res[2];
    double sx = (double)bev_start[0] - resx*0.5;
    double sy = (double)bev_start[1] - resy*0.5;
    double sz = (double)bev_start[2] - resz*0.5;

    int cx = (int)((gx - sx)/resx);
    int cy = (int)((gy - sy)/resy);
    int cz = (int)((gz - sz)/resz);

    int cell = -1;
    if (cx >= 0 && cx < X_ && cy >= 0 && cy < Y_ && cz == 0)
        cell = (b*X_ + cx)*Y_ + cy;
    rank[p] = cell;
}

// 2h x 4w patch per wave (8 points): half 0 = row h, half 1 = row h+1.
// Per w-step: vertical pair-merge via shfl_xor(32), then horizontal running
// merge per half (exact cell-equality dedupe). Flush = pk-f16 atomic into
// replica q&3. Captures 2D spatial runs (both h and w adjacency).
__global__ __launch_bounds__(256)
void scatter_2x4(const float2* __restrict__ feat2,
                 const int* __restrict__ rank,
                 __half2* __restrict__ stage) {
    int tid  = blockIdx.x * blockDim.x + threadIdx.x;
    int q    = tid >> 6;            // patch id, [0, NPTS/8)
    int lane = tid & 63;
    int half = lane >> 5;
    int k    = lane & 31;

    int s  = q / 88;                // slice (bn*D_ + d)
    int r  = q % 88;
    int hp = r / 11;                // h-pair 0..7
    int wb = r % 11;                // w-block 0..10
    int pbase = s*(H_*W_) + (hp*2 + half)*W_ + wb*4;

    __half2* rep = stage + (size_t)(q & (KREP-1)) * ((size_t)NCELL*32);

    int runCell = -1;
    float rx = 0.f, ry = 0.f;
    #pragma unroll
    for (int i = 0; i < 4; ++i) {
        int p = pbase + i;
        int c = rank[p];                       // uniform within half (broadcast)
        float vx = 0.f, vy = 0.f;
        if (c >= 0) { float2 v = feat2[(size_t)p*32 + k]; vx = v.x; vy = v.y; }

        // vertical merge: top half absorbs bottom when cells match
        int   oc = __shfl_xor(c, 32);
        float ox = __shfl_xor(vx, 32);
        float oy = __shfl_xor(vy, 32);
        if (c >= 0 && c == oc) {
            if (half == 0) { vx += ox; vy += oy; }
            else c = -1;
        }

        // horizontal running merge per half
        if (c >= 0) {
            if (c == runCell) { rx += vx; ry += vy; }
            else {
                if (runCell >= 0) {
                    __half2 hv; hv.x = __float2half(rx); hv.y = __float2half(ry);
                    pk_add_f16(&rep[(size_t)runCell*32 + k], hv);
                }
                runCell = c; rx = vx; ry = vy;
            }
        }
    }
    if (runCell >= 0) {
        __half2 hv; hv.x = __float2half(rx); hv.y = __float2half(ry);
        pk_add_f16(&rep[(size_t)runCell*32 + k], hv);
    }
}

// Sum 4 fp16 replicas (B, X*Y, C) -> (B, C, X*Y) f32 output.
__global__ __launch_bounds__(512)
void trans_h2(const __half2* __restrict__ stage, float* __restrict__ out) {
    __shared__ float tile[64][65];
    int b   = blockIdx.y;
    int xy0 = blockIdx.x * 64;
    int tx  = threadIdx.x & 31;    // half2 index (channel pair)
    int ty  = threadIdx.x >> 5;    // 0..15

    const size_t rstride = (size_t)NCELL*32;
    #pragma unroll
    for (int i = 0; i < 4; ++i) {
        int r = ty + i*16;         // 0..63
        size_t idx = ((size_t)b*(X_*Y_) + xy0 + r)*32 + tx;
        float sx = 0.f, sy = 0.f;
        #pragma unroll
        for (int kk = 0; kk < KREP; ++kk) {
            float2 f = __half22float2(stage[kk*rstride + idx]);
            sx += f.x; sy += f.y;
        }
        tile[r][2*tx]   = sx;
        tile[r][2*tx+1] = sy;
    }
    __syncthreads();
    int cw = threadIdx.x >> 6;     // 0..7
    int j  = threadIdx.x & 63;
    #pragma unroll
    for (int k = 0; k < 8; ++k) {
        int c = cw*8 + k;
        out[((size_t)(b*C_ + c))*(X_*Y_) + xy0 + j] = tile[j][c];
    }
}

// Fallback (tiny ws): direct f32 atomics into (B,C,X,Y) output.
__global__ __launch_bounds__(256)
void scatter_fallback(const float* __restrict__ feat,
                      const int* __restrict__ rank,
                      float* __restrict__ dst) {
    int tid  = blockIdx.x * blockDim.x + threadIdx.x;
    int p    = tid >> 6;
    int lane = tid & 63;
    if (p >= NPTS) return;
    int cell = rank[p];
    if (cell < 0) return;
    int b = cell / (X_*Y_);
    int xy = cell % (X_*Y_);
    float v = feat[(size_t)p*C_ + lane];
    unsafeAtomicAdd(&dst[((size_t)(b*C_ + lane))*(X_*Y_) + xy], v);
}

extern "C" void kernel_launch(void* const* d_in, const int* in_sizes, int n_in,
                              void* d_out, int out_size, void* d_ws, size_t ws_size,
                              hipStream_t stream) {
    const float* feat       = (const float*)d_in[0];
    const float* post_trans = (const float*)d_in[1];
    const float* post_rots  = (const float*)d_in[2];
    const float* intr       = (const float*)d_in[3];
    const float* extr       = (const float*)d_in[4];
    const float* frustum    = (const float*)d_in[5];
    const float* bev_res    = (const float*)d_in[6];
    const float* bev_start  = (const float*)d_in[7];
    float* out = (float*)d_out;

    // ws layout
    char* base = (char*)d_ws;
    double* mats   = (double*)base;                    size_t off = 4096;
    int* rank      = (int*)(base + off);               off += (size_t)NPTS*4;
    off = (off + 511) & ~(size_t)511;
    __half2* stage = (__half2*)(base + off);
    const size_t stage_bytes = (size_t)KREP * NCELL * C_ * 2;  // 40.96 MB
    off += stage_bytes;
    bool have_ws = (ws_size >= off);

    hipLaunchKernelGGL(prep_kernel, dim3(1), dim3(16), 0, stream,
                       post_rots, intr, extr, mats);

    const int pt_blocks = (NPTS + 255) / 256;

    geom_kernel<<<pt_blocks, 256, 0, stream>>>(post_trans, frustum, bev_res,
                                               bev_start, mats, rank);

    if (have_ws) {
        hipMemsetAsync(stage, 0, stage_bytes, stream);
        const int sc_blocks = (int)(((size_t)(NPTS/8)*64 + 255) / 256);  // 10824
        scatter_2x4<<<sc_blocks, 256, 0, stream>>>((const float2*)feat, rank, stage);
        trans_h2<<<dim3((X_*Y_)/64, B_), 512, 0, stream>>>(stage, out);
    } else {
        hipMemsetAsync(out, 0, (size_t)out_size*sizeof(float), stream);
        const int wv_blocks = (int)(((size_t)NPTS*64 + 255) / 256);
        scatter_fallback<<<wv_blocks, 256, 0, stream>>>(feat, rank, out);
    }
}

// Round 15
// 75.506 us; speedup vs baseline: 1.0243x; 1.0243x over previous
//
#include <hip/hip_runtime.h>
#include <hip/hip_fp16.h>

#define B_ 2
#define N_ 6
#define D_ 41
#define H_ 16
#define W_ 44
#define C_ 64
#define X_ 200
#define Y_ 200
#define NPTS (B_*N_*D_*H_*W_)   // 346368 (multiple of 8; == 1353*256)
#define NBN (B_*N_)             // 12
#define NCELL (B_*X_*Y_)        // 80000
#define MAT_STRIDE 24
#define KREP 4                  // stage replicas (hot-line contention / KREP)
#define STAGE_F4 ((size_t)KREP*NCELL*32*8/16)  // float4 count of stage = 2,560,000

// Deterministic HW packed-fp16 atomic add (gfx90a+/gfx950): 2 channels per op.
__device__ inline void pk_add_f16(__half2* addr, __half2 val) {
    unsigned int u = *reinterpret_cast<unsigned int*>(&val);
    asm volatile("global_atomic_pk_add_f16 %0, %1, off"
                 :: "v"((unsigned long long)(uintptr_t)addr), "v"(u)
                 : "memory");
}

__device__ inline void inv3x3(const double m[9], double out[9]) {
    double a=m[0],b=m[1],c=m[2],d=m[3],e=m[4],f=m[5],g=m[6],h=m[7],i=m[8];
    double A  =  (e*i - f*h);
    double Bm = -(d*i - f*g);
    double Cm =  (d*h - e*g);
    double det = a*A + b*Bm + c*Cm;
    double id = 1.0/det;
    out[0] = A*id;   out[1] = -(b*i - c*h)*id; out[2] =  (b*f - c*e)*id;
    out[3] = Bm*id;  out[4] =  (a*i - c*g)*id; out[5] = -(a*f - c*d)*id;
    out[6] = Cm*id;  out[7] = -(a*h - b*g)*id; out[8] =  (a*e - b*d)*id;
}

// One thread per (b,n): inv(post_rots), comb = rot(inv(extr)) @ inv(K), trans.
__global__ void prep_kernel(const float* __restrict__ post_rots,
                            const float* __restrict__ intr,
                            const float* __restrict__ extr,
                            double* __restrict__ mats) {
    int bn = threadIdx.x;
    if (bn >= NBN) return;

    double pr[9], prinv[9], kk[9], kin[9];
    for (int i=0;i<9;i++) pr[i] = (double)post_rots[bn*9+i];
    inv3x3(pr, prinv);
    for (int i=0;i<9;i++) kk[i] = (double)intr[bn*9+i];
    inv3x3(kk, kin);

    const float* E = extr + bn*16;
    double a00=E[0], a01=E[1], a02=E[2], a03=E[3];
    double a10=E[4], a11=E[5], a12=E[6], a13=E[7];
    double a20=E[8], a21=E[9], a22=E[10], a23=E[11];
    double a30=E[12], a31=E[13], a32=E[14], a33=E[15];

    double s0=a00*a11-a10*a01, s1=a00*a12-a10*a02, s2=a00*a13-a10*a03;
    double s3=a01*a12-a11*a02, s4=a01*a13-a11*a03, s5=a02*a13-a12*a03;
    double c5=a22*a33-a32*a23, c4=a21*a33-a31*a23, c3=a21*a32-a31*a22;
    double c2=a20*a33-a30*a23, c1=a20*a32-a30*a22, c0=a20*a31-a30*a21;
    double det = s0*c5 - s1*c4 + s2*c3 + s3*c2 - s4*c1 + s5*c0;
    double iv = 1.0/det;

    double rot[9], trans[3];
    rot[0] = ( a11*c5 - a12*c4 + a13*c3)*iv;
    rot[1] = (-a01*c5 + a02*c4 - a03*c3)*iv;
    rot[2] = ( a31*s5 - a32*s4 + a33*s3)*iv;
    trans[0]=(-a21*s5 + a22*s4 - a23*s3)*iv;
    rot[3] = (-a10*c5 + a12*c2 - a13*c1)*iv;
    rot[4] = ( a00*c5 - a02*c2 + a03*c1)*iv;
    rot[5] = (-a30*s5 + a32*s2 - a33*s1)*iv;
    trans[1]=( a20*s5 - a22*s2 + a23*s1)*iv;
    rot[6] = ( a10*c4 - a11*c2 + a13*c0)*iv;
    rot[7] = (-a00*c4 + a01*c2 - a03*c0)*iv;
    rot[8] = ( a30*s4 - a31*s2 + a33*s0)*iv;
    trans[2]=(-a20*s4 + a21*s2 - a23*s0)*iv;

    double comb[9];
    for (int i=0;i<3;i++) for (int j=0;j<3;j++)
        comb[i*3+j] = rot[i*3+0]*kin[0+j] + rot[i*3+1]*kin[3+j] + rot[i*3+2]*kin[6+j];

    double* o = mats + (size_t)bn*MAT_STRIDE;
    for (int i=0;i<9;i++) o[i]   = prinv[i];
    for (int i=0;i<9;i++) o[9+i] = comb[i];
    for (int i=0;i<3;i++) o[18+i]= trans[i];
}

// One THREAD per point: cell id (or -1). FUSED: also zeroes the 41 MB stage
// (grid-stride float4 stores) — store-BW overlaps the f64 VALU geometry,
// replacing the runtime's slow fillBuffer dispatch.
__global__ __launch_bounds__(256)
void geom_kernel(const float* __restrict__ post_trans,
                 const float* __restrict__ frustum,
                 const float* __restrict__ bev_res,
                 const float* __restrict__ bev_start,
                 const double* __restrict__ mats,
                 int* __restrict__ rank,
                 float4* __restrict__ stage4) {
    int p = blockIdx.x * blockDim.x + threadIdx.x;

    // stage zero: 2,560,000 float4 over 346,368 threads (8 grid-stride iters)
    const float4 z4 = make_float4(0.f, 0.f, 0.f, 0.f);
    for (size_t i = (size_t)p; i < STAGE_F4; i += (size_t)NPTS)
        stage4[i] = z4;

    if (p >= NPTS) return;

    int w = p % W_; int t = p / W_;
    int h = t % H_;  t /= H_;
    int d = t % D_;  t /= D_;
    int bn = t;      int b = bn / N_;

    const double* M = mats + (size_t)bn*MAT_STRIDE;
    int fidx = ((d*H_ + h)*W_ + w)*3;
    double fx = (double)frustum[fidx+0];
    double fy = (double)frustum[fidx+1];
    double fz = (double)frustum[fidx+2];

    double px = fx - (double)post_trans[bn*3+0];
    double py = fy - (double)post_trans[bn*3+1];
    double pz = fz - (double)post_trans[bn*3+2];

    double q0 = M[0]*px + M[1]*py + M[2]*pz;
    double q1 = M[3]*px + M[4]*py + M[5]*pz;
    double q2 = M[6]*px + M[7]*py + M[8]*pz;

    double r0 = q0*q2, r1 = q1*q2, r2 = q2;

    double gx = M[9]*r0  + M[10]*r1 + M[11]*r2 + M[18];
    double gy = M[12]*r0 + M[13]*r1 + M[14]*r2 + M[19];
    double gz = M[15]*r0 + M[16]*r1 + M[17]*r2 + M[20];

    double resx = (double)bev_res[0], resy = (double)bev_res[1], resz = (double)bev_res[2];
    double sx = (double)bev_start[0] - resx*0.5;
    double sy = (double)bev_start[1] - resy*0.5;
    double sz = (double)bev_start[2] - resz*0.5;

    int cx = (int)((gx - sx)/resx);
    int cy = (int)((gy - sy)/resy);
    int cz = (int)((gz - sz)/resz);

    int cell = -1;
    if (cx >= 0 && cx < X_ && cy >= 0 && cy < Y_ && cz == 0)
        cell = (b*X_ + cx)*Y_ + cy;
    rank[p] = cell;
}

// 2h x 4w patch per wave (8 points): half 0 = row h, half 1 = row h+1.
// Vertical pair-merge via shfl_xor(32) + horizontal running merge per half.
// Flush = pk-f16 atomic into replica q&3.
__global__ __launch_bounds__(256)
void scatter_2x4(const float2* __restrict__ feat2,
                 const int* __restrict__ rank,
                 __half2* __restrict__ stage) {
    int tid  = blockIdx.x * blockDim.x + threadIdx.x;
    int q    = tid >> 6;            // patch id, [0, NPTS/8)
    int lane = tid & 63;
    int half = lane >> 5;
    int k    = lane & 31;

    int s  = q / 88;                // slice (bn*D_ + d)
    int r  = q % 88;
    int hp = r / 11;                // h-pair 0..7
    int wb = r % 11;                // w-block 0..10
    int pbase = s*(H_*W_) + (hp*2 + half)*W_ + wb*4;

    __half2* rep = stage + (size_t)(q & (KREP-1)) * ((size_t)NCELL*32);

    int runCell = -1;
    float rx = 0.f, ry = 0.f;
    #pragma unroll
    for (int i = 0; i < 4; ++i) {
        int p = pbase + i;
        int c = rank[p];                       // uniform within half (broadcast)
        float vx = 0.f, vy = 0.f;
        if (c >= 0) { float2 v = feat2[(size_t)p*32 + k]; vx = v.x; vy = v.y; }

        // vertical merge: top half absorbs bottom when cells match
        int   oc = __shfl_xor(c, 32);
        float ox = __shfl_xor(vx, 32);
        float oy = __shfl_xor(vy, 32);
        if (c >= 0 && c == oc) {
            if (half == 0) { vx += ox; vy += oy; }
            else c = -1;
        }

        // horizontal running merge per half
        if (c >= 0) {
            if (c == runCell) { rx += vx; ry += vy; }
            else {
                if (runCell >= 0) {
                    __half2 hv; hv.x = __float2half(rx); hv.y = __float2half(ry);
                    pk_add_f16(&rep[(size_t)runCell*32 + k], hv);
                }
                runCell = c; rx = vx; ry = vy;
            }
        }
    }
    if (runCell >= 0) {
        __half2 hv; hv.x = __float2half(rx); hv.y = __float2half(ry);
        pk_add_f16(&rep[(size_t)runCell*32 + k], hv);
    }
}

// Sum 4 fp16 replicas (B, X*Y, C) -> (B, C, X*Y) f32 output.
__global__ __launch_bounds__(512)
void trans_h2(const __half2* __restrict__ stage, float* __restrict__ out) {
    __shared__ float tile[64][65];
    int b   = blockIdx.y;
    int xy0 = blockIdx.x * 64;
    int tx  = threadIdx.x & 31;    // half2 index (channel pair)
    int ty  = threadIdx.x >> 5;    // 0..15

    const size_t rstride = (size_t)NCELL*32;
    #pragma unroll
    for (int i = 0; i < 4; ++i) {
        int r = ty + i*16;         // 0..63
        size_t idx = ((size_t)b*(X_*Y_) + xy0 + r)*32 + tx;
        float sx = 0.f, sy = 0.f;
        #pragma unroll
        for (int kk = 0; kk < KREP; ++kk) {
            float2 f = __half22float2(stage[kk*rstride + idx]);
            sx += f.x; sy += f.y;
        }
        tile[r][2*tx]   = sx;
        tile[r][2*tx+1] = sy;
    }
    __syncthreads();
    int cw = threadIdx.x >> 6;     // 0..7
    int j  = threadIdx.x & 63;
    #pragma unroll
    for (int k = 0; k < 8; ++k) {
        int c = cw*8 + k;
        out[((size_t)(b*C_ + c))*(X_*Y_) + xy0 + j] = tile[j][c];
    }
}

// Fallback (tiny ws): direct f32 atomics into (B,C,X,Y) output.
__global__ __launch_bounds__(256)
void geom_only(const float* __restrict__ post_trans,
               const float* __restrict__ frustum,
               const float* __restrict__ bev_res,
               const float* __restrict__ bev_start,
               const double* __restrict__ mats,
               int* __restrict__ rank) {
    int p = blockIdx.x * blockDim.x + threadIdx.x;
    if (p >= NPTS) return;
    int w = p % W_; int t = p / W_;
    int h = t % H_;  t /= H_;
    int d = t % D_;  t /= D_;
    int bn = t;      int b = bn / N_;
    const double* M = mats + (size_t)bn*MAT_STRIDE;
    int fidx = ((d*H_ + h)*W_ + w)*3;
    double fx = (double)frustum[fidx+0];
    double fy = (double)frustum[fidx+1];
    double fz = (double)frustum[fidx+2];
    double px = fx - (double)post_trans[bn*3+0];
    double py = fy - (double)post_trans[bn*3+1];
    double pz = fz - (double)post_trans[bn*3+2];
    double q0 = M[0]*px + M[1]*py + M[2]*pz;
    double q1 = M[3]*px + M[4]*py + M[5]*pz;
    double q2 = M[6]*px + M[7]*py + M[8]*pz;
    double r0 = q0*q2, r1 = q1*q2, r2 = q2;
    double gx = M[9]*r0  + M[10]*r1 + M[11]*r2 + M[18];
    double gy = M[12]*r0 + M[13]*r1 + M[14]*r2 + M[19];
    double gz = M[15]*r0 + M[16]*r1 + M[17]*r2 + M[20];
    double resx = (double)bev_res[0], resy = (double)bev_res[1], resz = (double)bev_res[2];
    double sx = (double)bev_start[0] - resx*0.5;
    double sy = (double)bev_start[1] - resy*0.5;
    double sz = (double)bev_start[2] - resz*0.5;
    int cx = (int)((gx - sx)/resx);
    int cy = (int)((gy - sy)/resy);
    int cz = (int)((gz - sz)/resz);
    int cell = -1;
    if (cx >= 0 && cx < X_ && cy >= 0 && cy < Y_ && cz == 0)
        cell = (b*X_ + cx)*Y_ + cy;
    rank[p] = cell;
}

__global__ __launch_bounds__(256)
void scatter_fallback(const float* __restrict__ feat,
                      const int* __restrict__ rank,
                      float* __restrict__ dst) {
    int tid  = blockIdx.x * blockDim.x + threadIdx.x;
    int p    = tid >> 6;
    int lane = tid & 63;
    if (p >= NPTS) return;
    int cell = rank[p];
    if (cell < 0) return;
    int b = cell / (X_*Y_);
    int xy = cell % (X_*Y_);
    float v = feat[(size_t)p*C_ + lane];
    unsafeAtomicAdd(&dst[((size_t)(b*C_ + lane))*(X_*Y_) + xy], v);
}

extern "C" void kernel_launch(void* const* d_in, const int* in_sizes, int n_in,
                              void* d_out, int out_size, void* d_ws, size_t ws_size,
                              hipStream_t stream) {
    const float* feat       = (const float*)d_in[0];
    const float* post_trans = (const float*)d_in[1];
    const float* post_rots  = (const float*)d_in[2];
    const float* intr       = (const float*)d_in[3];
    const float* extr       = (const float*)d_in[4];
    const float* frustum    = (const float*)d_in[5];
    const float* bev_res    = (const float*)d_in[6];
    const float* bev_start  = (const float*)d_in[7];
    float* out = (float*)d_out;

    // ws layout
    char* base = (char*)d_ws;
    double* mats   = (double*)base;                    size_t off = 4096;
    int* rank      = (int*)(base + off);               off += (size_t)NPTS*4;
    off = (off + 511) & ~(size_t)511;
    __half2* stage = (__half2*)(base + off);
    const size_t stage_bytes = (size_t)KREP * NCELL * C_ * 2;  // 40.96 MB
    off += stage_bytes;
    bool have_ws = (ws_size >= off);

    hipLaunchKernelGGL(prep_kernel, dim3(1), dim3(16), 0, stream,
                       post_rots, intr, extr, mats);

    const int pt_blocks = (NPTS + 255) / 256;   // 1353

    if (have_ws) {
        geom_kernel<<<pt_blocks, 256, 0, stream>>>(post_trans, frustum, bev_res,
                                                   bev_start, mats, rank,
                                                   (float4*)stage);
        const int sc_blocks = (int)(((size_t)(NPTS/8)*64 + 255) / 256);  // 10824
        scatter_2x4<<<sc_blocks, 256, 0, stream>>>((const float2*)feat, rank, stage);
        trans_h2<<<dim3((X_*Y_)/64, B_), 512, 0, stream>>>(stage, out);
    } else {
        hipMemsetAsync(out, 0, (size_t)out_size*sizeof(float), stream);
        geom_only<<<pt_blocks, 256, 0, stream>>>(post_trans, frustum, bev_res,
                                                 bev_start, mats, rank);
        const int wv_blocks = (int)(((size_t)NPTS*64 + 255) / 256);
        scatter_fallback<<<wv_blocks, 256, 0, stream>>>(feat, rank, out);
    }
}

// Round 16
// 74.547 us; speedup vs baseline: 1.0375x; 1.0129x over previous
//
#include <hip/hip_runtime.h>
#include <hip/hip_fp16.h>

#define B_ 2
#define N_ 6
#define D_ 41
#define H_ 16
#define W_ 44
#define C_ 64
#define X_ 200
#define Y_ 200
#define NPTS (B_*N_*D_*H_*W_)   // 346368
#define NBN (B_*N_)             // 12
#define NCELL (B_*X_*Y_)        // 80000
#define MAT_STRIDE 24
#define KREP 4                  // stage replicas (hot-line contention / KREP)
#define STAGE_F4 ((size_t)KREP*NCELL*32*8/16)  // float4 count of stage = 2,560,000
#define NWAVE_SC (NBN*H_*(W_/2))               // 4224 waves in d-run scatter

// Packed-fp16 atomic add. _nc variant: no "memory" clobber -> compiler may
// pipeline the (disjoint) feat/rank loads across flushes.
__device__ inline void pk_add_f16_nc(__half2* addr, __half2 val) {
    unsigned int u = *reinterpret_cast<unsigned int*>(&val);
    asm volatile("global_atomic_pk_add_f16 %0, %1, off"
                 :: "v"((unsigned long long)(uintptr_t)addr), "v"(u));
}

__device__ inline void inv3x3(const double m[9], double out[9]) {
    double a=m[0],b=m[1],c=m[2],d=m[3],e=m[4],f=m[5],g=m[6],h=m[7],i=m[8];
    double A  =  (e*i - f*h);
    double Bm = -(d*i - f*g);
    double Cm =  (d*h - e*g);
    double det = a*A + b*Bm + c*Cm;
    double id = 1.0/det;
    out[0] = A*id;   out[1] = -(b*i - c*h)*id; out[2] =  (b*f - c*e)*id;
    out[3] = Bm*id;  out[4] =  (a*i - c*g)*id; out[5] = -(a*f - c*d)*id;
    out[6] = Cm*id;  out[7] = -(a*h - b*g)*id; out[8] =  (a*e - b*d)*id;
}

// One thread per (b,n): inv(post_rots), comb = rot(inv(extr)) @ inv(K), trans.
__global__ void prep_kernel(const float* __restrict__ post_rots,
                            const float* __restrict__ intr,
                            const float* __restrict__ extr,
                            double* __restrict__ mats) {
    int bn = threadIdx.x;
    if (bn >= NBN) return;

    double pr[9], prinv[9], kk[9], kin[9];
    for (int i=0;i<9;i++) pr[i] = (double)post_rots[bn*9+i];
    inv3x3(pr, prinv);
    for (int i=0;i<9;i++) kk[i] = (double)intr[bn*9+i];
    inv3x3(kk, kin);

    const float* E = extr + bn*16;
    double a00=E[0], a01=E[1], a02=E[2], a03=E[3];
    double a10=E[4], a11=E[5], a12=E[6], a13=E[7];
    double a20=E[8], a21=E[9], a22=E[10], a23=E[11];
    double a30=E[12], a31=E[13], a32=E[14], a33=E[15];

    double s0=a00*a11-a10*a01, s1=a00*a12-a10*a02, s2=a00*a13-a10*a03;
    double s3=a01*a12-a11*a02, s4=a01*a13-a11*a03, s5=a02*a13-a12*a03;
    double c5=a22*a33-a32*a23, c4=a21*a33-a31*a23, c3=a21*a32-a31*a22;
    double c2=a20*a33-a30*a23, c1=a20*a32-a30*a22, c0=a20*a31-a30*a21;
    double det = s0*c5 - s1*c4 + s2*c3 + s3*c2 - s4*c1 + s5*c0;
    double iv = 1.0/det;

    double rot[9], trans[3];
    rot[0] = ( a11*c5 - a12*c4 + a13*c3)*iv;
    rot[1] = (-a01*c5 + a02*c4 - a03*c3)*iv;
    rot[2] = ( a31*s5 - a32*s4 + a33*s3)*iv;
    trans[0]=(-a21*s5 + a22*s4 - a23*s3)*iv;
    rot[3] = (-a10*c5 + a12*c2 - a13*c1)*iv;
    rot[4] = ( a00*c5 - a02*c2 + a03*c1)*iv;
    rot[5] = (-a30*s5 + a32*s2 - a33*s1)*iv;
    trans[1]=( a20*s5 - a22*s2 + a23*s1)*iv;
    rot[6] = ( a10*c4 - a11*c2 + a13*c0)*iv;
    rot[7] = (-a00*c4 + a01*c2 - a03*c0)*iv;
    rot[8] = ( a30*s4 - a31*s2 + a33*s0)*iv;
    trans[2]=(-a20*s4 + a21*s2 - a23*s0)*iv;

    double comb[9];
    for (int i=0;i<3;i++) for (int j=0;j<3;j++)
        comb[i*3+j] = rot[i*3+0]*kin[0+j] + rot[i*3+1]*kin[3+j] + rot[i*3+2]*kin[6+j];

    double* o = mats + (size_t)bn*MAT_STRIDE;
    for (int i=0;i<9;i++) o[i]   = prinv[i];
    for (int i=0;i<9;i++) o[9+i] = comb[i];
    for (int i=0;i<3;i++) o[18+i]= trans[i];
}

// One THREAD per point: cell id (or -1). FUSED: zeroes the 41 MB stage
// (grid-stride float4 stores overlap the f64 VALU geometry).
__global__ __launch_bounds__(256)
void geom_kernel(const float* __restrict__ post_trans,
                 const float* __restrict__ frustum,
                 const float* __restrict__ bev_res,
                 const float* __restrict__ bev_start,
                 const double* __restrict__ mats,
                 int* __restrict__ rank,
                 float4* __restrict__ stage4) {
    int p = blockIdx.x * blockDim.x + threadIdx.x;

    const float4 z4 = make_float4(0.f, 0.f, 0.f, 0.f);
    for (size_t i = (size_t)p; i < STAGE_F4; i += (size_t)NPTS)
        stage4[i] = z4;

    if (p >= NPTS) return;

    int w = p % W_; int t = p / W_;
    int h = t % H_;  t /= H_;
    int d = t % D_;  t /= D_;
    int bn = t;      int b = bn / N_;

    const double* M = mats + (size_t)bn*MAT_STRIDE;
    int fidx = ((d*H_ + h)*W_ + w)*3;
    double fx = (double)frustum[fidx+0];
    double fy = (double)frustum[fidx+1];
    double fz = (double)frustum[fidx+2];

    double px = fx - (double)post_trans[bn*3+0];
    double py = fy - (double)post_trans[bn*3+1];
    double pz = fz - (double)post_trans[bn*3+2];

    double q0 = M[0]*px + M[1]*py + M[2]*pz;
    double q1 = M[3]*px + M[4]*py + M[5]*pz;
    double q2 = M[6]*px + M[7]*py + M[8]*pz;

    double r0 = q0*q2, r1 = q1*q2, r2 = q2;

    double gx = M[9]*r0  + M[10]*r1 + M[11]*r2 + M[18];
    double gy = M[12]*r0 + M[13]*r1 + M[14]*r2 + M[19];
    double gz = M[15]*r0 + M[16]*r1 + M[17]*r2 + M[20];

    double resx = (double)bev_res[0], resy = (double)bev_res[1], resz = (double)bev_res[2];
    double sx = (double)bev_start[0] - resx*0.5;
    double sy = (double)bev_start[1] - resy*0.5;
    double sz = (double)bev_start[2] - resz*0.5;

    int cx = (int)((gx - sx)/resx);
    int cy = (int)((gy - sy)/resy);
    int cz = (int)((gz - sz)/resz);

    int cell = -1;
    if (cx >= 0 && cx < X_ && cy >= 0 && cy < Y_ && cz == 0)
        cell = (b*X_ + cx)*Y_ + cy;
    rank[p] = cell;
}

// D-RUN scatter: one wave per (bn, h, w-pair); each 32-lane half owns pixel
// column (h,w) and iterates d=0..40 with a running cell merge. Central pixels
// (the HOT cells) have near-zero cell drift per d-step -> 41 flushes collapse
// to ~1-3, cutting atomic ops exactly where line serialization bites.
// 1-deep software prefetch; flush asm has no memory clobber so loads pipeline.
__global__ __launch_bounds__(256)
void scatter_druns(const float2* __restrict__ feat2,
                   const int* __restrict__ rank,
                   __half2* __restrict__ stage) {
    int tid  = blockIdx.x * blockDim.x + threadIdx.x;
    int q    = tid >> 6;            // [0, 4224)
    int lane = tid & 63;
    int half = lane >> 5;
    int k    = lane & 31;
    if (q >= NWAVE_SC) return;

    int wp = q % (W_/2);
    int t  = q / (W_/2);
    int h  = t % H_;
    int bn = t / H_;
    int w  = wp*2 + half;

    __half2* rep = stage + (size_t)(q & (KREP-1)) * ((size_t)NCELL*32);

    const int pstride = H_*W_;      // 704 points between consecutive d
    int p = (bn*D_*H_ + h)*W_ + w;  // d = 0

    int   c = rank[p];
    float2 v = feat2[(size_t)p*32 + k];

    int runCell = -1;
    float rx = 0.f, ry = 0.f;

    for (int d = 0; d < D_; ++d) {
        int   cn = -1;
        float2 vn = make_float2(0.f, 0.f);
        if (d + 1 < D_) {
            int pn = p + pstride;
            cn = rank[pn];
            vn = feat2[(size_t)pn*32 + k];   // unconditional: pn always valid
            p = pn;
        }
        if (c >= 0) {
            if (c == runCell) { rx += v.x; ry += v.y; }
            else {
                if (runCell >= 0) {
                    __half2 hv; hv.x = __float2half(rx); hv.y = __float2half(ry);
                    pk_add_f16_nc(&rep[(size_t)runCell*32 + k], hv);
                }
                runCell = c; rx = v.x; ry = v.y;
            }
        }
        c = cn; v = vn;
    }
    if (runCell >= 0) {
        __half2 hv; hv.x = __float2half(rx); hv.y = __float2half(ry);
        pk_add_f16_nc(&rep[(size_t)runCell*32 + k], hv);
    }
}

// Sum 4 fp16 replicas (B, X*Y, C) -> (B, C, X*Y) f32 output.
__global__ __launch_bounds__(512)
void trans_h2(const __half2* __restrict__ stage, float* __restrict__ out) {
    __shared__ float tile[64][65];
    int b   = blockIdx.y;
    int xy0 = blockIdx.x * 64;
    int tx  = threadIdx.x & 31;    // half2 index (channel pair)
    int ty  = threadIdx.x >> 5;    // 0..15

    const size_t rstride = (size_t)NCELL*32;
    #pragma unroll
    for (int i = 0; i < 4; ++i) {
        int r = ty + i*16;         // 0..63
        size_t idx = ((size_t)b*(X_*Y_) + xy0 + r)*32 + tx;
        float sx = 0.f, sy = 0.f;
        #pragma unroll
        for (int kk = 0; kk < KREP; ++kk) {
            float2 f = __half22float2(stage[kk*rstride + idx]);
            sx += f.x; sy += f.y;
        }
        tile[r][2*tx]   = sx;
        tile[r][2*tx+1] = sy;
    }
    __syncthreads();
    int cw = threadIdx.x >> 6;     // 0..7
    int j  = threadIdx.x & 63;
    #pragma unroll
    for (int k = 0; k < 8; ++k) {
        int c = cw*8 + k;
        out[((size_t)(b*C_ + c))*(X_*Y_) + xy0 + j] = tile[j][c];
    }
}

// Fallback path (tiny ws).
__global__ __launch_bounds__(256)
void geom_only(const float* __restrict__ post_trans,
               const float* __restrict__ frustum,
               const float* __restrict__ bev_res,
               const float* __restrict__ bev_start,
               const double* __restrict__ mats,
               int* __restrict__ rank) {
    int p = blockIdx.x * blockDim.x + threadIdx.x;
    if (p >= NPTS) return;
    int w = p % W_; int t = p / W_;
    int h = t % H_;  t /= H_;
    int d = t % D_;  t /= D_;
    int bn = t;      int b = bn / N_;
    const double* M = mats + (size_t)bn*MAT_STRIDE;
    int fidx = ((d*H_ + h)*W_ + w)*3;
    double fx = (double)frustum[fidx+0];
    double fy = (double)frustum[fidx+1];
    double fz = (double)frustum[fidx+2];
    double px = fx - (double)post_trans[bn*3+0];
    double py = fy - (double)post_trans[bn*3+1];
    double pz = fz - (double)post_trans[bn*3+2];
    double q0 = M[0]*px + M[1]*py + M[2]*pz;
    double q1 = M[3]*px + M[4]*py + M[5]*pz;
    double q2 = M[6]*px + M[7]*py + M[8]*pz;
    double r0 = q0*q2, r1 = q1*q2, r2 = q2;
    double gx = M[9]*r0  + M[10]*r1 + M[11]*r2 + M[18];
    double gy = M[12]*r0 + M[13]*r1 + M[14]*r2 + M[19];
    double gz = M[15]*r0 + M[16]*r1 + M[17]*r2 + M[20];
    double resx = (double)bev_res[0], resy = (double)bev_res[1], resz = (double)bev_res[2];
    double sx = (double)bev_start[0] - resx*0.5;
    double sy = (double)bev_start[1] - resy*0.5;
    double sz = (double)bev_start[2] - resz*0.5;
    int cx = (int)((gx - sx)/resx);
    int cy = (int)((gy - sy)/resy);
    int cz = (int)((gz - sz)/resz);
    int cell = -1;
    if (cx >= 0 && cx < X_ && cy >= 0 && cy < Y_ && cz == 0)
        cell = (b*X_ + cx)*Y_ + cy;
    rank[p] = cell;
}

__global__ __launch_bounds__(256)
void scatter_fallback(const float* __restrict__ feat,
                      const int* __restrict__ rank,
                      float* __restrict__ dst) {
    int tid  = blockIdx.x * blockDim.x + threadIdx.x;
    int p    = tid >> 6;
    int lane = tid & 63;
    if (p >= NPTS) return;
    int cell = rank[p];
    if (cell < 0) return;
    int b = cell / (X_*Y_);
    int xy = cell % (X_*Y_);
    float v = feat[(size_t)p*C_ + lane];
    unsafeAtomicAdd(&dst[((size_t)(b*C_ + lane))*(X_*Y_) + xy], v);
}

extern "C" void kernel_launch(void* const* d_in, const int* in_sizes, int n_in,
                              void* d_out, int out_size, void* d_ws, size_t ws_size,
                              hipStream_t stream) {
    const float* feat       = (const float*)d_in[0];
    const float* post_trans = (const float*)d_in[1];
    const float* post_rots  = (const float*)d_in[2];
    const float* intr       = (const float*)d_in[3];
    const float* extr       = (const float*)d_in[4];
    const float* frustum    = (const float*)d_in[5];
    const float* bev_res    = (const float*)d_in[6];
    const float* bev_start  = (const float*)d_in[7];
    float* out = (float*)d_out;

    // ws layout
    char* base = (char*)d_ws;
    double* mats   = (double*)base;                    size_t off = 4096;
    int* rank      = (int*)(base + off);               off += (size_t)NPTS*4;
    off = (off + 511) & ~(size_t)511;
    __half2* stage = (__half2*)(base + off);
    const size_t stage_bytes = (size_t)KREP * NCELL * C_ * 2;  // 40.96 MB
    off += stage_bytes;
    bool have_ws = (ws_size >= off);

    hipLaunchKernelGGL(prep_kernel, dim3(1), dim3(16), 0, stream,
                       post_rots, intr, extr, mats);

    const int pt_blocks = (NPTS + 255) / 256;   // 1353

    if (have_ws) {
        geom_kernel<<<pt_blocks, 256, 0, stream>>>(post_trans, frustum, bev_res,
                                                   bev_start, mats, rank,
                                                   (float4*)stage);
        const int sc_blocks = (NWAVE_SC * 64) / 256;   // 1056
        scatter_druns<<<sc_blocks, 256, 0, stream>>>((const float2*)feat, rank, stage);
        trans_h2<<<dim3((X_*Y_)/64, B_), 512, 0, stream>>>(stage, out);
    } else {
        hipMemsetAsync(out, 0, (size_t)out_size*sizeof(float), stream);
        geom_only<<<pt_blocks, 256, 0, stream>>>(post_trans, frustum, bev_res,
                                                 bev_start, mats, rank);
        const int wv_blocks = (int)(((size_t)NPTS*64 + 255) / 256);
        scatter_fallback<<<wv_blocks, 256, 0, stream>>>(feat, rank, out);
    }
}

// Round 17
// 69.318 us; speedup vs baseline: 1.1158x; 1.0754x over previous
//
#include <hip/hip_runtime.h>
#include <hip/hip_fp16.h>

#define B_ 2
#define N_ 6
#define D_ 41
#define H_ 16
#define W_ 44
#define C_ 64
#define X_ 200
#define Y_ 200
#define NPTS (B_*N_*D_*H_*W_)   // 346368 == 1353*256
#define NBN (B_*N_)             // 12
#define PPI (D_*H_*W_)          // 28864 points per (b,n) image
#define NCELL (B_*X_*Y_)        // 80000
#define KREP 4                  // stage replicas (hot-line contention / KREP)
#define STAGE_F4 ((size_t)KREP*NCELL*32*8/16)  // float4 count of stage = 2,560,000
#define NWAVE_SC (NBN*H_*(W_/2))               // 4224 waves in d-run scatter

// Packed-fp16 atomic add (no memory clobber -> loads pipeline across flushes).
__device__ inline void pk_add_f16_nc(__half2* addr, __half2 val) {
    unsigned int u = *reinterpret_cast<unsigned int*>(&val);
    asm volatile("global_atomic_pk_add_f16 %0, %1, off"
                 :: "v"((unsigned long long)(uintptr_t)addr), "v"(u));
}

__device__ inline void inv3x3(const double m[9], double out[9]) {
    double a=m[0],b=m[1],c=m[2],d=m[3],e=m[4],f=m[5],g=m[6],h=m[7],i=m[8];
    double A  =  (e*i - f*h);
    double Bm = -(d*i - f*g);
    double Cm =  (d*h - e*g);
    double det = a*A + b*Bm + c*Cm;
    double id = 1.0/det;
    out[0] = A*id;   out[1] = -(b*i - c*h)*id; out[2] =  (b*f - c*e)*id;
    out[3] = Bm*id;  out[4] =  (a*i - c*g)*id; out[5] = -(a*f - c*d)*id;
    out[6] = Cm*id;  out[7] = -(a*h - b*g)*id; out[8] =  (a*e - b*d)*id;
}

// Per-(b,n) matrices, closed-form adjugate (registers only, no scratch):
// o[0..8]=inv(post_rots), o[9..17]=rot(inv(extr))@inv(K), o[18..20]=trans.
__device__ inline void make_mats(int bn,
                                 const float* __restrict__ post_rots,
                                 const float* __restrict__ intr,
                                 const float* __restrict__ extr,
                                 double* o) {
    double pr[9], prinv[9], kk[9], kin[9];
    for (int i=0;i<9;i++) pr[i] = (double)post_rots[bn*9+i];
    inv3x3(pr, prinv);
    for (int i=0;i<9;i++) kk[i] = (double)intr[bn*9+i];
    inv3x3(kk, kin);

    const float* E = extr + bn*16;
    double a00=E[0], a01=E[1], a02=E[2], a03=E[3];
    double a10=E[4], a11=E[5], a12=E[6], a13=E[7];
    double a20=E[8], a21=E[9], a22=E[10], a23=E[11];
    double a30=E[12], a31=E[13], a32=E[14], a33=E[15];

    double s0=a00*a11-a10*a01, s1=a00*a12-a10*a02, s2=a00*a13-a10*a03;
    double s3=a01*a12-a11*a02, s4=a01*a13-a11*a03, s5=a02*a13-a12*a03;
    double c5=a22*a33-a32*a23, c4=a21*a33-a31*a23, c3=a21*a32-a31*a22;
    double c2=a20*a33-a30*a23, c1=a20*a32-a30*a22, c0=a20*a31-a30*a21;
    double det = s0*c5 - s1*c4 + s2*c3 + s3*c2 - s4*c1 + s5*c0;
    double iv = 1.0/det;

    double rot[9], trans[3];
    rot[0] = ( a11*c5 - a12*c4 + a13*c3)*iv;
    rot[1] = (-a01*c5 + a02*c4 - a03*c3)*iv;
    rot[2] = ( a31*s5 - a32*s4 + a33*s3)*iv;
    trans[0]=(-a21*s5 + a22*s4 - a23*s3)*iv;
    rot[3] = (-a10*c5 + a12*c2 - a13*c1)*iv;
    rot[4] = ( a00*c5 - a02*c2 + a03*c1)*iv;
    rot[5] = (-a30*s5 + a32*s2 - a33*s1)*iv;
    trans[1]=( a20*s5 - a22*s2 + a23*s1)*iv;
    rot[6] = ( a10*c4 - a11*c2 + a13*c0)*iv;
    rot[7] = (-a00*c4 + a01*c2 - a03*c0)*iv;
    rot[8] = ( a30*s4 - a31*s2 + a33*s0)*iv;
    trans[2]=(-a20*s4 + a21*s2 - a23*s0)*iv;

    for (int i=0;i<9;i++) o[i] = prinv[i];
    for (int i=0;i<3;i++) for (int j=0;j<3;j++)
        o[9 + i*3+j] = rot[i*3+0]*kin[0+j] + rot[i*3+1]*kin[3+j] + rot[i*3+2]*kin[6+j];
    for (int i=0;i<3;i++) o[18+i] = trans[i];
}

// One THREAD per point: cell id (or -1). FUSED: (a) per-block mats in LDS
// (threads 0-1 compute the 1-2 bn this block spans — no prep kernel),
// (b) zeroes the 41 MB stage via grid-stride float4 stores (overlaps VALU).
__global__ __launch_bounds__(256)
void geom_kernel(const float* __restrict__ post_trans,
                 const float* __restrict__ post_rots,
                 const float* __restrict__ intr,
                 const float* __restrict__ extr,
                 const float* __restrict__ frustum,
                 const float* __restrict__ bev_res,
                 const float* __restrict__ bev_start,
                 int* __restrict__ rank,
                 float4* __restrict__ stage4) {
    __shared__ double Msh[2][21];
    int p0 = blockIdx.x * 256;
    int p  = p0 + threadIdx.x;
    int bn0 = p0 / PPI;
    int bnl = (p0 + 255) / PPI;           // bnl - bn0 <= 1 (256 << PPI)

    // stage zero: all threads (grid-stride float4)
    const float4 z4 = make_float4(0.f, 0.f, 0.f, 0.f);
    for (size_t i = (size_t)p; i < STAGE_F4; i += (size_t)NPTS)
        stage4[i] = z4;

    // block-local matrices
    if (threadIdx.x < 2) {
        int bn = bn0 + (int)threadIdx.x;
        if (bn <= bnl && bn < NBN)
            make_mats(bn, post_rots, intr, extr, Msh[threadIdx.x]);
    }
    __syncthreads();

    if (p >= NPTS) return;

    int w = p % W_; int t = p / W_;
    int h = t % H_;  t /= H_;
    int d = t % D_;  t /= D_;
    int bn = t;      int b = bn / N_;

    const double* M = Msh[bn - bn0];
    int fidx = ((d*H_ + h)*W_ + w)*3;
    double fx = (double)frustum[fidx+0];
    double fy = (double)frustum[fidx+1];
    double fz = (double)frustum[fidx+2];

    double px = fx - (double)post_trans[bn*3+0];
    double py = fy - (double)post_trans[bn*3+1];
    double pz = fz - (double)post_trans[bn*3+2];

    double q0 = M[0]*px + M[1]*py + M[2]*pz;
    double q1 = M[3]*px + M[4]*py + M[5]*pz;
    double q2 = M[6]*px + M[7]*py + M[8]*pz;

    double r0 = q0*q2, r1 = q1*q2, r2 = q2;

    double gx = M[9]*r0  + M[10]*r1 + M[11]*r2 + M[18];
    double gy = M[12]*r0 + M[13]*r1 + M[14]*r2 + M[19];
    double gz = M[15]*r0 + M[16]*r1 + M[17]*r2 + M[20];

    double resx = (double)bev_res[0], resy = (double)bev_res[1], resz = (double)bev_res[2];
    double sx = (double)bev_start[0] - resx*0.5;
    double sy = (double)bev_start[1] - resy*0.5;
    double sz = (double)bev_start[2] - resz*0.5;

    int cx = (int)((gx - sx)/resx);
    int cy = (int)((gy - sy)/resy);
    int cz = (int)((gz - sz)/resz);

    int cell = -1;
    if (cx >= 0 && cx < X_ && cy >= 0 && cy < Y_ && cz == 0)
        cell = (b*X_ + cx)*Y_ + cy;
    rank[p] = cell;
}

// D-RUN scatter: one wave per (bn, h, w-pair); each 32-lane half owns a pixel
// column and iterates d=0..40 with a running cell merge (hot central pixels
// collapse to ~1-3 flushes). 1-deep software prefetch.
__global__ __launch_bounds__(256)
void scatter_druns(const float2* __restrict__ feat2,
                   const int* __restrict__ rank,
                   __half2* __restrict__ stage) {
    int tid  = blockIdx.x * blockDim.x + threadIdx.x;
    int q    = tid >> 6;            // [0, 4224)
    int lane = tid & 63;
    int half = lane >> 5;
    int k    = lane & 31;
    if (q >= NWAVE_SC) return;

    int wp = q % (W_/2);
    int t  = q / (W_/2);
    int h  = t % H_;
    int bn = t / H_;
    int w  = wp*2 + half;

    __half2* rep = stage + (size_t)(q & (KREP-1)) * ((size_t)NCELL*32);

    const int pstride = H_*W_;      // 704 points between consecutive d
    int p = (bn*D_*H_ + h)*W_ + w;  // d = 0

    int   c = rank[p];
    float2 v = feat2[(size_t)p*32 + k];

    int runCell = -1;
    float rx = 0.f, ry = 0.f;

    for (int d = 0; d < D_; ++d) {
        int   cn = -1;
        float2 vn = make_float2(0.f, 0.f);
        if (d + 1 < D_) {
            int pn = p + pstride;
            cn = rank[pn];
            vn = feat2[(size_t)pn*32 + k];
            p = pn;
        }
        if (c >= 0) {
            if (c == runCell) { rx += v.x; ry += v.y; }
            else {
                if (runCell >= 0) {
                    __half2 hv; hv.x = __float2half(rx); hv.y = __float2half(ry);
                    pk_add_f16_nc(&rep[(size_t)runCell*32 + k], hv);
                }
                runCell = c; rx = v.x; ry = v.y;
            }
        }
        c = cn; v = vn;
    }
    if (runCell >= 0) {
        __half2 hv; hv.x = __float2half(rx); hv.y = __float2half(ry);
        pk_add_f16_nc(&rep[(size_t)runCell*32 + k], hv);
    }
}

// Sum 4 fp16 replicas (B, X*Y, C) -> (B, C, X*Y) f32 output.
__global__ __launch_bounds__(512)
void trans_h2(const __half2* __restrict__ stage, float* __restrict__ out) {
    __shared__ float tile[64][65];
    int b   = blockIdx.y;
    int xy0 = blockIdx.x * 64;
    int tx  = threadIdx.x & 31;    // half2 index (channel pair)
    int ty  = threadIdx.x >> 5;    // 0..15

    const size_t rstride = (size_t)NCELL*32;
    #pragma unroll
    for (int i = 0; i < 4; ++i) {
        int r = ty + i*16;         // 0..63
        size_t idx = ((size_t)b*(X_*Y_) + xy0 + r)*32 + tx;
        float sx = 0.f, sy = 0.f;
        #pragma unroll
        for (int kk = 0; kk < KREP; ++kk) {
            float2 f = __half22float2(stage[kk*rstride + idx]);
            sx += f.x; sy += f.y;
        }
        tile[r][2*tx]   = sx;
        tile[r][2*tx+1] = sy;
    }
    __syncthreads();
    int cw = threadIdx.x >> 6;     // 0..7
    int j  = threadIdx.x & 63;
    #pragma unroll
    for (int k = 0; k < 8; ++k) {
        int c = cw*8 + k;
        out[((size_t)(b*C_ + c))*(X_*Y_) + xy0 + j] = tile[j][c];
    }
}

// Fallback path (tiny ws): fused-mats geom (no stage), then direct f32 atomics.
__global__ __launch_bounds__(256)
void geom_only(const float* __restrict__ post_trans,
               const float* __restrict__ post_rots,
               const float* __restrict__ intr,
               const float* __restrict__ extr,
               const float* __restrict__ frustum,
               const float* __restrict__ bev_res,
               const float* __restrict__ bev_start,
               int* __restrict__ rank) {
    __shared__ double Msh[2][21];
    int p0 = blockIdx.x * 256;
    int p  = p0 + threadIdx.x;
    int bn0 = p0 / PPI;
    int bnl = (p0 + 255) / PPI;
    if (threadIdx.x < 2) {
        int bn = bn0 + (int)threadIdx.x;
        if (bn <= bnl && bn < NBN)
            make_mats(bn, post_rots, intr, extr, Msh[threadIdx.x]);
    }
    __syncthreads();
    if (p >= NPTS) return;
    int w = p % W_; int t = p / W_;
    int h = t % H_;  t /= H_;
    int d = t % D_;  t /= D_;
    int bn = t;      int b = bn / N_;
    const double* M = Msh[bn - bn0];
    int fidx = ((d*H_ + h)*W_ + w)*3;
    double fx = (double)frustum[fidx+0];
    double fy = (double)frustum[fidx+1];
    double fz = (double)frustum[fidx+2];
    double px = fx - (double)post_trans[bn*3+0];
    double py = fy - (double)post_trans[bn*3+1];
    double pz = fz - (double)post_trans[bn*3+2];
    double q0 = M[0]*px + M[1]*py + M[2]*pz;
    double q1 = M[3]*px + M[4]*py + M[5]*pz;
    double q2 = M[6]*px + M[7]*py + M[8]*pz;
    double r0 = q0*q2, r1 = q1*q2, r2 = q2;
    double gx = M[9]*r0  + M[10]*r1 + M[11]*r2 + M[18];
    double gy = M[12]*r0 + M[13]*r1 + M[14]*r2 + M[19];
    double gz = M[15]*r0 + M[16]*r1 + M[17]*r2 + M[20];
    double resx = (double)bev_res[0], resy = (double)bev_res[1], resz = (double)bev_res[2];
    double sx = (double)bev_start[0] - resx*0.5;
    double sy = (double)bev_start[1] - resy*0.5;
    double sz = (double)bev_start[2] - resz*0.5;
    int cx = (int)((gx - sx)/resx);
    int cy = (int)((gy - sy)/resy);
    int cz = (int)((gz - sz)/resz);
    int cell = -1;
    if (cx >= 0 && cx < X_ && cy >= 0 && cy < Y_ && cz == 0)
        cell = (b*X_ + cx)*Y_ + cy;
    rank[p] = cell;
}

__global__ __launch_bounds__(256)
void scatter_fallback(const float* __restrict__ feat,
                      const int* __restrict__ rank,
                      float* __restrict__ dst) {
    int tid  = blockIdx.x * blockDim.x + threadIdx.x;
    int p    = tid >> 6;
    int lane = tid & 63;
    if (p >= NPTS) return;
    int cell = rank[p];
    if (cell < 0) return;
    int b = cell / (X_*Y_);
    int xy = cell % (X_*Y_);
    float v = feat[(size_t)p*C_ + lane];
    unsafeAtomicAdd(&dst[((size_t)(b*C_ + lane))*(X_*Y_) + xy], v);
}

extern "C" void kernel_launch(void* const* d_in, const int* in_sizes, int n_in,
                              void* d_out, int out_size, void* d_ws, size_t ws_size,
                              hipStream_t stream) {
    const float* feat       = (const float*)d_in[0];
    const float* post_trans = (const float*)d_in[1];
    const float* post_rots  = (const float*)d_in[2];
    const float* intr       = (const float*)d_in[3];
    const float* extr       = (const float*)d_in[4];
    const float* frustum    = (const float*)d_in[5];
    const float* bev_res    = (const float*)d_in[6];
    const float* bev_start  = (const float*)d_in[7];
    float* out = (float*)d_out;

    // ws layout (no mats buffer anymore)
    char* base = (char*)d_ws;
    int* rank      = (int*)base;                       size_t off = (size_t)NPTS*4;
    off = (off + 511) & ~(size_t)511;
    __half2* stage = (__half2*)(base + off);
    const size_t stage_bytes = (size_t)KREP * NCELL * C_ * 2;  // 40.96 MB
    off += stage_bytes;
    bool have_ws = (ws_size >= off);

    const int pt_blocks = NPTS / 256;   // 1353 exactly

    if (have_ws) {
        geom_kernel<<<pt_blocks, 256, 0, stream>>>(post_trans, post_rots, intr, extr,
                                                   frustum, bev_res, bev_start,
                                                   rank, (float4*)stage);
        const int sc_blocks = (NWAVE_SC * 64) / 256;   // 1056
        scatter_druns<<<sc_blocks, 256, 0, stream>>>((const float2*)feat, rank, stage);
        trans_h2<<<dim3((X_*Y_)/64, B_), 512, 0, stream>>>(stage, out);
    } else {
        hipMemsetAsync(out, 0, (size_t)out_size*sizeof(float), stream);
        geom_only<<<pt_blocks, 256, 0, stream>>>(post_trans, post_rots, intr, extr,
                                                 frustum, bev_res, bev_start, rank);
        const int wv_blocks = (int)(((size_t)NPTS*64 + 255) / 256);
        scatter_fallback<<<wv_blocks, 256, 0, stream>>>(feat, rank, out);
    }
}